// Round 3
// baseline (248.753 us; speedup 1.0000x reference)
//
#include <hip/hip_runtime.h>
#include <hip/hip_bf16.h>

typedef __bf16 bf16;
typedef __attribute__((ext_vector_type(8))) __bf16 bf16x8;
typedef __attribute__((ext_vector_type(4))) __bf16 bf16x4;
typedef __attribute__((ext_vector_type(4))) float floatx4;

// async global->LDS, 16B per lane. LDS dest must be wave-uniform base + lane*16.
__device__ __forceinline__ void gl_lds16(const bf16* g, bf16* l) {
    __builtin_amdgcn_global_load_lds(
        (const __attribute__((address_space(1))) unsigned int*)g,
        (__attribute__((address_space(3))) unsigned int*)l,
        16, 0, 0);
}

// ---------------------------------------------------------------- cast fp32 -> bf16 (x4 vectorized)
__global__ __launch_bounds__(256) void cast_f32_bf16_v4(const float* __restrict__ in,
                                                        bf16* __restrict__ out,
                                                        long long n4) {
    long long i = (long long)blockIdx.x * 256 + threadIdx.x;
    if (i < n4) {
        float4 v = ((const float4*)in)[i];
        bf16x4 o;
        o[0] = (bf16)v.x; o[1] = (bf16)v.y; o[2] = (bf16)v.z; o[3] = (bf16)v.w;
        ((bf16x4*)out)[i] = o;
    }
}

// ---------------------------------------------------------------- fp32 [R,C] -> bf16 [C,R] transpose
__global__ __launch_bounds__(256) void cast_transpose(const float* __restrict__ in,
                                                      bf16* __restrict__ out,
                                                      int R, int C) {
    __shared__ float tile[32][33];
    const long long bz = blockIdx.z;
    in  += bz * (long long)R * C;
    out += bz * (long long)R * C;
    const int r0 = blockIdx.x * 32, c0 = blockIdx.y * 32;
    const int tx = threadIdx.x & 31, ty = threadIdx.x >> 5;
#pragma unroll
    for (int i = 0; i < 32; i += 8)
        tile[ty + i][tx] = in[(long long)(r0 + ty + i) * C + (c0 + tx)];
    __syncthreads();
#pragma unroll
    for (int i = 0; i < 32; i += 8)
        out[(long long)(c0 + ty + i) * R + (r0 + tx)] = (bf16)tile[tx][ty + i];
}

__device__ __forceinline__ float fast_tanh(float v) {
    // 1 - 2/(e^{2v}+1): safe at +-inf (exp overflow -> 1, underflow -> -1)
    float e = __expf(2.0f * v);
    return 1.0f - 2.0f / (e + 1.0f);
}

// ---------------------------------------------------------------- 128x128-tile MFMA GEMM, NT form
// C[M,N] = A[M,K] * B[N,K]^T; A,B row-major bf16, K%32==0, M%128==0, N%128==0.
// MODE 0: store bf16 (plain)                       -- proj
// MODE 1: store bf16 exp(tanh(v)) + rowsum atomics -- scores -> unnormalized softmax numerator
// MODE 2: store fp32 v / rowsum[row]               -- PV with fused softmax divide
// Epilogues are LDS-bounced for coalesced dwordx4 global stores.
template <int MODE>
__global__ __launch_bounds__(256) void gemm128_nt(const bf16* __restrict__ A,
                                                  const bf16* __restrict__ Bm,
                                                  void* __restrict__ Cout,
                                                  float* __restrict__ rowsum,
                                                  int M, int N, int K,
                                                  long long batchA, long long batchB,
                                                  long long batchC, long long batchR) {
    const long long bz = blockIdx.z;
    A  += bz * batchA;
    Bm += bz * batchB;

    // union: K-loop staging (16 KB) | bf16 bounce 128x136 (34.0 KB) | f32 bounce 64x132 + 128 rs (34.3 KB)
    __shared__ __align__(16) char lds_raw[34816];
    bf16* As = (bf16*)lds_raw;
    bf16* Bs = As + 128 * 32;

    const int t    = threadIdx.x;
    const int lane = t & 63;
    const int wave = t >> 6;
    const int quad = lane >> 4;
    const int l16  = lane & 15;

    const int m0 = blockIdx.x * 128;
    const int n0 = blockIdx.y * 128;
    const int wm = (wave >> 1) * 64;
    const int wn = (wave & 1) * 64;

    floatx4 acc[4][4] = {};

    const int r0 = t >> 2;             // 0..63
    const int c0 = (t & 3) * 8;        // 0/8/16/24

    const bf16* Ag0 = A + (long long)(m0 + r0) * K + c0;
    const bf16* Ag1 = A + (long long)(m0 + 64 + r0) * K + c0;
    const bf16* Bg0 = Bm + (long long)(n0 + r0) * K + c0;
    const bf16* Bg1 = Bm + (long long)(n0 + 64 + r0) * K + c0;

    for (int k0 = 0; k0 < K; k0 += 32) {
        gl_lds16(Ag0 + k0, &As[t * 8]);
        gl_lds16(Ag1 + k0, &As[(t + 256) * 8]);
        gl_lds16(Bg0 + k0, &Bs[t * 8]);
        gl_lds16(Bg1 + k0, &Bs[(t + 256) * 8]);
        __syncthreads();

        bf16x8 af[4], bfr[4];
#pragma unroll
        for (int i = 0; i < 4; ++i)
            af[i] = *(const bf16x8*)(&As[(wm + i * 16 + l16) * 32 + quad * 8]);
#pragma unroll
        for (int j = 0; j < 4; ++j)
            bfr[j] = *(const bf16x8*)(&Bs[(wn + j * 16 + l16) * 32 + quad * 8]);

#pragma unroll
        for (int i = 0; i < 4; ++i)
#pragma unroll
            for (int j = 0; j < 4; ++j)
                acc[i][j] = __builtin_amdgcn_mfma_f32_16x16x32_bf16(af[i], bfr[j], acc[i][j], 0, 0, 0);

        __syncthreads();   // also guards LDS reuse by the epilogue
    }

    if (MODE == 0 || MODE == 1) {
        bf16* Cb = (bf16*)lds_raw;   // [128][136] (pad 8: stride 68 dwords, conflict-free-ish)
        float ps[4][4];              // per-lane partial row sums (MODE 1)
#pragma unroll
        for (int i = 0; i < 4; ++i)
#pragma unroll
            for (int r = 0; r < 4; ++r) ps[i][r] = 0.f;

#pragma unroll
        for (int i = 0; i < 4; ++i)
#pragma unroll
            for (int j = 0; j < 4; ++j)
#pragma unroll
                for (int r = 0; r < 4; ++r) {
                    float v = acc[i][j][r];
                    if (MODE == 1) { v = __expf(fast_tanh(v)); ps[i][r] += v; }
                    Cb[(wm + i * 16 + quad * 4 + r) * 136 + (wn + j * 16 + l16)] = (bf16)v;
                }

        if (MODE == 1) {
            // reduce over the 16 l16-lanes (same rows within a quad), 1 atomic/row/wave
#pragma unroll
            for (int i = 0; i < 4; ++i)
#pragma unroll
                for (int r = 0; r < 4; ++r) {
                    float s = ps[i][r];
#pragma unroll
                    for (int msk = 1; msk < 16; msk <<= 1) s += __shfl_xor(s, msk);
                    if (l16 == 0)
                        atomicAdd(&rowsum[bz * batchR + m0 + wm + i * 16 + quad * 4 + r], s);
                }
        }
        __syncthreads();
        // coalesced readback: 128 rows x 16 chunks(16B)
        bf16* Cg = (bf16*)Cout + bz * batchC;
#pragma unroll
        for (int c = 0; c < 8; ++c) {
            int ch  = t + c * 256;
            int row = ch >> 4, k16 = ch & 15;
            bf16x8 pk = *(const bf16x8*)&Cb[row * 136 + k16 * 8];
            *(bf16x8*)(Cg + (long long)(m0 + row) * N + n0 + k16 * 8) = pk;
        }
    } else {
        float* Cf = (float*)lds_raw;            // [64][132]
        float* rs = (float*)lds_raw + 64 * 132; // [128]
        if (t < 128) rs[t] = rowsum[bz * batchR + m0 + t];
        __syncthreads();
        float* Og = (float*)Cout + bz * batchC;
#pragma unroll
        for (int half = 0; half < 2; ++half) {
            if (wm == half * 64) {
#pragma unroll
                for (int i = 0; i < 4; ++i)
#pragma unroll
                    for (int r = 0; r < 4; ++r) {
                        int rl = i * 16 + quad * 4 + r;
                        float inv = 1.0f / rs[half * 64 + rl];
#pragma unroll
                        for (int j = 0; j < 4; ++j)
                            Cf[rl * 132 + (wn + j * 16 + l16)] = acc[i][j][r] * inv;
                    }
            }
            __syncthreads();
            // 64 rows x 32 chunks(16B)
#pragma unroll
            for (int c = 0; c < 8; ++c) {
                int ch  = t + c * 256;
                int row = ch >> 5, c4 = ch & 31;
                floatx4 pk = *(const floatx4*)&Cf[row * 132 + c4 * 4];
                *(floatx4*)(Og + (long long)(m0 + half * 64 + row) * N + n0 + c4 * 4) = pk;
            }
            __syncthreads();
        }
    }
}

// ----------------------------------------------------------------
extern "C" void kernel_launch(void* const* d_in, const int* in_sizes, int n_in,
                              void* d_out, int out_size, void* d_ws, size_t ws_size,
                              hipStream_t stream) {
    const int B = 8, S = 2048, D = 512;
    const float* x = (const float*)d_in[0];
    const float* W = (const float*)d_in[1];
    float* out = (float*)d_out;

    const size_t nx = (size_t)B * S * D;
    const size_t nw = (size_t)D * D;

    char* ws = (char*)d_ws;
    auto al = [](size_t v) { return (v + 255) & ~(size_t)255; };
    size_t off = 0;
    bf16* xb = (bf16*)(ws + off); off = al(off + nx * 2);          // x bf16 [B,S,D]
    bf16* xt = (bf16*)(ws + off); off = al(off + nx * 2);          // x^T bf16 [B,D,S]
    bf16* pb = (bf16*)(ws + off); off = al(off + nx * 2);          // proj bf16 [B,S,D]
    bf16* wt = (bf16*)(ws + off); off = al(off + nw * 2);          // W^T bf16 [D,D]
    float* rsum = (float*)(ws + off); off = al(off + (size_t)B * S * 4);  // softmax denominators
    bf16* sb = (bf16*)(ws + off);                                  // P_unnorm bf16
    const size_t full_need = off + (size_t)B * S * S * 2;
    const bool batched = (ws_size >= full_need);

    hipMemsetAsync(rsum, 0, (size_t)B * S * 4, stream);

    cast_f32_bf16_v4<<<(int)((nx / 4 + 255) / 256), 256, 0, stream>>>(x, xb, (long long)(nx / 4));
    { dim3 g(S / 32, D / 32, B); cast_transpose<<<g, 256, 0, stream>>>(x, xt, S, D); }
    { dim3 g(D / 32, D / 32, 1); cast_transpose<<<g, 256, 0, stream>>>(W, wt, D, D); }

    // proj: pb[BS,D] = xb[BS,D] @ wt^T
    {
        dim3 g(B * S / 128, D / 128, 1);
        gemm128_nt<0><<<g, 256, 0, stream>>>(xb, wt, (void*)pb, nullptr, B * S, D, D, 0, 0, 0, 0);
    }

    const long long sd = (long long)S * D;
    const long long ss = (long long)S * S;

    if (batched) {
        // P_un = exp(tanh(pb @ xb^T)) + rowsums
        dim3 g2(S / 128, S / 128, B);
        gemm128_nt<1><<<g2, 256, 0, stream>>>(pb, xb, (void*)sb, rsum, S, S, D, sd, sd, ss, S);
        // out = (P_un @ xt^T) / rowsum
        dim3 g4(S / 128, D / 128, B);
        gemm128_nt<2><<<g4, 256, 0, stream>>>(sb, xt, (void*)out, rsum, S, D, S, ss, sd, sd, S);
    } else {
        for (int b = 0; b < B; ++b) {
            dim3 g2(S / 128, S / 128, 1);
            gemm128_nt<1><<<g2, 256, 0, stream>>>(pb + (size_t)b * sd, xb + (size_t)b * sd,
                                                  (void*)sb, rsum + (size_t)b * S, S, S, D, 0, 0, 0, 0);
            dim3 g4(S / 128, D / 128, 1);
            gemm128_nt<2><<<g4, 256, 0, stream>>>(sb, xt + (size_t)b * sd,
                                                  (void*)(out + (size_t)b * sd), rsum + (size_t)b * S,
                                                  S, D, S, 0, 0, 0, 0);
        }
    }
}

// Round 4
// 233.717 us; speedup vs baseline: 1.0643x; 1.0643x over previous
//
#include <hip/hip_runtime.h>
#include <hip/hip_bf16.h>

typedef __bf16 bf16;
typedef __attribute__((ext_vector_type(8))) __bf16 bf16x8;
typedef __attribute__((ext_vector_type(4))) __bf16 bf16x4;
typedef __attribute__((ext_vector_type(4))) float floatx4;

// async global->LDS, 16B per lane. LDS dest must be wave-uniform base + lane*16.
__device__ __forceinline__ void gl_lds16(const bf16* g, bf16* l) {
    __builtin_amdgcn_global_load_lds(
        (const __attribute__((address_space(1))) unsigned int*)g,
        (__attribute__((address_space(3))) unsigned int*)l,
        16, 0, 0);
}

// ---------------------------------------------------------------- x fp32 [R,C] -> xb bf16 [R,C] AND xt bf16 [C,R]
// Reads x exactly once. block 256 = 32x8, 32x32 tile, padded LDS for the transpose path.
__global__ __launch_bounds__(256) void cast_both(const float* __restrict__ in,
                                                 bf16* __restrict__ outn,
                                                 bf16* __restrict__ outt,
                                                 int R, int C) {
    __shared__ float tile[32][33];
    const long long bz = blockIdx.z;
    in   += bz * (long long)R * C;
    outn += bz * (long long)R * C;
    outt += bz * (long long)R * C;
    const int r0 = blockIdx.x * 32, c0 = blockIdx.y * 32;
    const int tx = threadIdx.x & 31, ty = threadIdx.x >> 5;
#pragma unroll
    for (int i = 0; i < 32; i += 8) {
        float v = in[(long long)(r0 + ty + i) * C + (c0 + tx)];
        tile[ty + i][tx] = v;
        outn[(long long)(r0 + ty + i) * C + (c0 + tx)] = (bf16)v;
    }
    __syncthreads();
#pragma unroll
    for (int i = 0; i < 32; i += 8)
        outt[(long long)(c0 + ty + i) * R + (r0 + tx)] = (bf16)tile[tx][ty + i];
}

// ---------------------------------------------------------------- fp32 [R,C] -> bf16 [C,R] transpose (for W)
__global__ __launch_bounds__(256) void cast_transpose(const float* __restrict__ in,
                                                      bf16* __restrict__ out,
                                                      int R, int C) {
    __shared__ float tile[32][33];
    const int r0 = blockIdx.x * 32, c0 = blockIdx.y * 32;
    const int tx = threadIdx.x & 31, ty = threadIdx.x >> 5;
#pragma unroll
    for (int i = 0; i < 32; i += 8)
        tile[ty + i][tx] = in[(long long)(r0 + ty + i) * C + (c0 + tx)];
    __syncthreads();
#pragma unroll
    for (int i = 0; i < 32; i += 8)
        out[(long long)(c0 + ty + i) * R + (r0 + tx)] = (bf16)tile[tx][ty + i];
}

__device__ __forceinline__ float fast_tanh(float v) {
    // 1 - 2/(e^{2v}+1): safe at +-inf (exp overflow -> 1, underflow -> -1)
    float e = __expf(2.0f * v);
    return 1.0f - 2.0f / (e + 1.0f);
}

// ---------------------------------------------------------------- 128x128-tile MFMA GEMM, NT form
// C[M,N] = A[M,K] * B[N,K]^T; A,B row-major bf16, K%32==0, M%128==0, N%128==0.
// MODE 0: store bf16 (plain)                          -- proj
// MODE 1: store bf16 exp(tanh(v)) + rowsum atomics    -- scores -> unnormalized softmax numerator
// MODE 2: store fp32 v / rowsum[row]                  -- PV with fused softmax divide
// Direct (strided) global stores: R2 evidence says K-loop occupancy, not the epilogue,
// is the limiter. LDS stays at 16 KB so VGPR (72) is the occupancy cap (7 blocks/CU).
template <int MODE>
__global__ __launch_bounds__(256) void gemm128_nt(const bf16* __restrict__ A,
                                                  const bf16* __restrict__ Bm,
                                                  void* __restrict__ Cout,
                                                  float* __restrict__ rowsum,
                                                  int M, int N, int K,
                                                  long long batchA, long long batchB,
                                                  long long batchC, long long batchR) {
    const long long bz = blockIdx.z;
    A  += bz * batchA;
    Bm += bz * batchB;

    __shared__ bf16 As[128 * 32];   // unpadded: required by global_load_lds lane layout
    __shared__ bf16 Bs[128 * 32];
    __shared__ float rs[128];       // MODE 2 only (512 B, no occupancy impact)

    const int t    = threadIdx.x;
    const int lane = t & 63;
    const int wave = t >> 6;
    const int quad = lane >> 4;
    const int l16  = lane & 15;

    const int m0 = blockIdx.x * 128;
    const int n0 = blockIdx.y * 128;
    const int wm = (wave >> 1) * 64;
    const int wn = (wave & 1) * 64;

    floatx4 acc[4][4] = {};

    const int r0 = t >> 2;             // 0..63
    const int c0 = (t & 3) * 8;        // 0/8/16/24

    const bf16* Ag0 = A + (long long)(m0 + r0) * K + c0;
    const bf16* Ag1 = A + (long long)(m0 + 64 + r0) * K + c0;
    const bf16* Bg0 = Bm + (long long)(n0 + r0) * K + c0;
    const bf16* Bg1 = Bm + (long long)(n0 + 64 + r0) * K + c0;

    for (int k0 = 0; k0 < K; k0 += 32) {
        gl_lds16(Ag0 + k0, &As[t * 8]);
        gl_lds16(Ag1 + k0, &As[(t + 256) * 8]);
        gl_lds16(Bg0 + k0, &Bs[t * 8]);
        gl_lds16(Bg1 + k0, &Bs[(t + 256) * 8]);
        __syncthreads();

        bf16x8 af[4], bfr[4];
#pragma unroll
        for (int i = 0; i < 4; ++i)
            af[i] = *(const bf16x8*)(&As[(wm + i * 16 + l16) * 32 + quad * 8]);
#pragma unroll
        for (int j = 0; j < 4; ++j)
            bfr[j] = *(const bf16x8*)(&Bs[(wn + j * 16 + l16) * 32 + quad * 8]);

#pragma unroll
        for (int i = 0; i < 4; ++i)
#pragma unroll
            for (int j = 0; j < 4; ++j)
                acc[i][j] = __builtin_amdgcn_mfma_f32_16x16x32_bf16(af[i], bfr[j], acc[i][j], 0, 0, 0);

        __syncthreads();
    }

    if (MODE == 0 || MODE == 1) {
        bf16* Cg = (bf16*)Cout + bz * batchC;
        float ps[4][4];
#pragma unroll
        for (int i = 0; i < 4; ++i)
#pragma unroll
            for (int r = 0; r < 4; ++r) ps[i][r] = 0.f;

#pragma unroll
        for (int i = 0; i < 4; ++i)
#pragma unroll
            for (int j = 0; j < 4; ++j)
#pragma unroll
                for (int r = 0; r < 4; ++r) {
                    float v = acc[i][j][r];
                    if (MODE == 1) { v = __expf(fast_tanh(v)); ps[i][r] += v; }
                    long long row = m0 + wm + i * 16 + quad * 4 + r;
                    long long col = n0 + wn + j * 16 + l16;
                    Cg[row * (long long)N + col] = (bf16)v;
                }

        if (MODE == 1) {
            // reduce over the 16 l16-lanes (same row within a quad), 1 atomic/row/wave
#pragma unroll
            for (int i = 0; i < 4; ++i)
#pragma unroll
                for (int r = 0; r < 4; ++r) {
                    float s = ps[i][r];
#pragma unroll
                    for (int msk = 1; msk < 16; msk <<= 1) s += __shfl_xor(s, msk);
                    if (l16 == 0)
                        atomicAdd(&rowsum[bz * batchR + m0 + wm + i * 16 + quad * 4 + r], s);
                }
        }
    } else {
        if (t < 128) rs[t] = rowsum[bz * batchR + m0 + t];
        __syncthreads();
        float* Og = (float*)Cout + bz * batchC;
#pragma unroll
        for (int i = 0; i < 4; ++i)
#pragma unroll
            for (int r = 0; r < 4; ++r) {
                float inv = 1.0f / rs[wm + i * 16 + quad * 4 + r];
                long long row = m0 + wm + i * 16 + quad * 4 + r;
#pragma unroll
                for (int j = 0; j < 4; ++j) {
                    long long col = n0 + wn + j * 16 + l16;
                    Og[row * (long long)N + col] = acc[i][j][r] * inv;
                }
            }
    }
}

// ----------------------------------------------------------------
extern "C" void kernel_launch(void* const* d_in, const int* in_sizes, int n_in,
                              void* d_out, int out_size, void* d_ws, size_t ws_size,
                              hipStream_t stream) {
    const int B = 8, S = 2048, D = 512;
    const float* x = (const float*)d_in[0];
    const float* W = (const float*)d_in[1];
    float* out = (float*)d_out;

    const size_t nx = (size_t)B * S * D;
    const size_t nw = (size_t)D * D;

    char* ws = (char*)d_ws;
    auto al = [](size_t v) { return (v + 255) & ~(size_t)255; };
    size_t off = 0;
    bf16* xb = (bf16*)(ws + off); off = al(off + nx * 2);          // x bf16 [B,S,D]
    bf16* xt = (bf16*)(ws + off); off = al(off + nx * 2);          // x^T bf16 [B,D,S]
    bf16* pb = (bf16*)(ws + off); off = al(off + nx * 2);          // proj bf16 [B,S,D]
    bf16* wt = (bf16*)(ws + off); off = al(off + nw * 2);          // W^T bf16 [D,D]
    float* rsum = (float*)(ws + off); off = al(off + (size_t)B * S * 4);  // softmax denominators
    bf16* sb = (bf16*)(ws + off);                                  // P_unnorm bf16
    const size_t full_need = off + (size_t)B * S * S * 2;
    const bool batched = (ws_size >= full_need);

    hipMemsetAsync(rsum, 0, (size_t)B * S * 4, stream);

    // xb + xt in one pass over x; wt from W
    { dim3 g(S / 32, D / 32, B); cast_both<<<g, 256, 0, stream>>>(x, xb, xt, S, D); }
    { dim3 g(D / 32, D / 32, 1); cast_transpose<<<g, 256, 0, stream>>>(W, wt, D, D); }

    // proj: pb[BS,D] = xb[BS,D] @ wt^T
    {
        dim3 g(B * S / 128, D / 128, 1);
        gemm128_nt<0><<<g, 256, 0, stream>>>(xb, wt, (void*)pb, nullptr, B * S, D, D, 0, 0, 0, 0);
    }

    const long long sd = (long long)S * D;
    const long long ss = (long long)S * S;

    if (batched) {
        // P_un = exp(tanh(pb @ xb^T)) + rowsums
        dim3 g2(S / 128, S / 128, B);
        gemm128_nt<1><<<g2, 256, 0, stream>>>(pb, xb, (void*)sb, rsum, S, S, D, sd, sd, ss, S);
        // out = (P_un @ xt^T) / rowsum
        dim3 g4(S / 128, D / 128, B);
        gemm128_nt<2><<<g4, 256, 0, stream>>>(sb, xt, (void*)out, rsum, S, D, S, ss, sd, sd, S);
    } else {
        for (int b = 0; b < B; ++b) {
            dim3 g2(S / 128, S / 128, 1);
            gemm128_nt<1><<<g2, 256, 0, stream>>>(pb + (size_t)b * sd, xb + (size_t)b * sd,
                                                  (void*)sb, rsum + (size_t)b * S, S, S, D, 0, 0, 0, 0);
            dim3 g4(S / 128, D / 128, 1);
            gemm128_nt<2><<<g4, 256, 0, stream>>>(sb, xt + (size_t)b * sd,
                                                  (void*)(out + (size_t)b * sd), rsum + (size_t)b * S,
                                                  S, D, S, 0, 0, 0, 0);
        }
    }
}

// Round 5
// 215.738 us; speedup vs baseline: 1.1530x; 1.0833x over previous
//
#include <hip/hip_runtime.h>
#include <hip/hip_bf16.h>

typedef __bf16 bf16;
typedef __attribute__((ext_vector_type(8))) __bf16 bf16x8;
typedef __attribute__((ext_vector_type(4))) float floatx4;

// async global->LDS, 16B per lane. LDS dest is wave-uniform base + lane*16 (fixed by HW);
// we therefore swizzle the GLOBAL source chunk, not the LDS destination.
__device__ __forceinline__ void gl_lds16(const bf16* g, bf16* l) {
    __builtin_amdgcn_global_load_lds(
        (const __attribute__((address_space(1))) unsigned int*)g,
        (__attribute__((address_space(3))) unsigned int*)l,
        16, 0, 0);
}

// ---------------------------------------------------------------- x fp32 [R,C] -> xb bf16 [R,C] AND xt bf16 [C,R]
__global__ __launch_bounds__(256) void cast_both(const float* __restrict__ in,
                                                 bf16* __restrict__ outn,
                                                 bf16* __restrict__ outt,
                                                 int R, int C) {
    __shared__ float tile[32][33];
    const long long bz = blockIdx.z;
    in   += bz * (long long)R * C;
    outn += bz * (long long)R * C;
    outt += bz * (long long)R * C;
    const int r0 = blockIdx.x * 32, c0 = blockIdx.y * 32;
    const int tx = threadIdx.x & 31, ty = threadIdx.x >> 5;
#pragma unroll
    for (int i = 0; i < 32; i += 8) {
        float v = in[(long long)(r0 + ty + i) * C + (c0 + tx)];
        tile[ty + i][tx] = v;
        outn[(long long)(r0 + ty + i) * C + (c0 + tx)] = (bf16)v;
    }
    __syncthreads();
#pragma unroll
    for (int i = 0; i < 32; i += 8)
        outt[(long long)(c0 + ty + i) * R + (r0 + tx)] = (bf16)tile[tx][ty + i];
}

// ---------------------------------------------------------------- fp32 [R,C] -> bf16 [C,R] (for W)
__global__ __launch_bounds__(256) void cast_transpose(const float* __restrict__ in,
                                                      bf16* __restrict__ out,
                                                      int R, int C) {
    __shared__ float tile[32][33];
    const int r0 = blockIdx.x * 32, c0 = blockIdx.y * 32;
    const int tx = threadIdx.x & 31, ty = threadIdx.x >> 5;
#pragma unroll
    for (int i = 0; i < 32; i += 8)
        tile[ty + i][tx] = in[(long long)(r0 + ty + i) * C + (c0 + tx)];
    __syncthreads();
#pragma unroll
    for (int i = 0; i < 32; i += 8)
        out[(long long)(c0 + ty + i) * R + (r0 + tx)] = (bf16)tile[tx][ty + i];
}

__device__ __forceinline__ float fast_tanh(float v) {
    float e = __expf(2.0f * v);
    return 1.0f - 2.0f / (e + 1.0f);
}

// ---------------------------------------------------------------- scores: 128x128 tile, BK=64, NT
// P = exp(tanh(A @ B^T)) stored bf16 + fp32 rowsum atomics. K%64==0, M,N%128==0.
// LDS staged via global_load_lds with XOR chunk swizzle (conflict-free frag reads).
__global__ __launch_bounds__(256) void gemm128_score(const bf16* __restrict__ A,
                                                     const bf16* __restrict__ Bm,
                                                     bf16* __restrict__ P,
                                                     float* __restrict__ rowsum,
                                                     int M, int N, int K,
                                                     long long batchA, long long batchB,
                                                     long long batchC, long long batchR) {
    const long long bz = blockIdx.z;
    A  += bz * batchA;
    Bm += bz * batchB;

    __shared__ bf16 As[128 * 64];   // 16 KB
    __shared__ bf16 Bs[128 * 64];   // 16 KB

    const int t    = threadIdx.x;
    const int lane = t & 63;
    const int wave = t >> 6;
    const int quad = lane >> 4;
    const int l16  = lane & 15;

    const int m0 = blockIdx.x * 128;
    const int n0 = blockIdx.y * 128;
    const int wm = (wave >> 1) * 64;
    const int wn = (wave & 1) * 64;

    floatx4 acc[4][4] = {};

    // staging: 1024 16B-chunks per matrix. LDS slot (r, cl) holds global (r, cl ^ (r&7)).
    // thread t stages slots t + 256*i -> row ra+32*i (ra&7 invariant), global col swizzled once.
    const int ra = t >> 3;
    const int ca = (((t & 7) ^ (ra & 7))) * 8;
    const long long rstep = 32LL * K;
    const bf16* Abase = A + (long long)(m0 + ra) * K + ca;
    const bf16* Bbase = Bm + (long long)(n0 + ra) * K + ca;

    // frag-read chunk offsets (bf16 elems): ((s*4+quad) ^ (l16&7)) * 8
    const int cq0 = ((quad) ^ (l16 & 7)) * 8;
    const int cq1 = ((4 + quad) ^ (l16 & 7)) * 8;

    for (int k0 = 0; k0 < K; k0 += 64) {
#pragma unroll
        for (int i = 0; i < 4; ++i) {
            gl_lds16(Abase + k0 + i * rstep, &As[(t + 256 * i) * 8]);
            gl_lds16(Bbase + k0 + i * rstep, &Bs[(t + 256 * i) * 8]);
        }
        __syncthreads();

#pragma unroll
        for (int s = 0; s < 2; ++s) {
            const int cq = s ? cq1 : cq0;
            bf16x8 af[4], bfr[4];
#pragma unroll
            for (int i = 0; i < 4; ++i)
                af[i] = *(const bf16x8*)(&As[(wm + i * 16 + l16) * 64 + cq]);
#pragma unroll
            for (int j = 0; j < 4; ++j)
                bfr[j] = *(const bf16x8*)(&Bs[(wn + j * 16 + l16) * 64 + cq]);
#pragma unroll
            for (int i = 0; i < 4; ++i)
#pragma unroll
                for (int j = 0; j < 4; ++j)
                    acc[i][j] = __builtin_amdgcn_mfma_f32_16x16x32_bf16(af[i], bfr[j], acc[i][j], 0, 0, 0);
        }
        __syncthreads();
    }

    bf16* Cg = P + bz * batchC;
#pragma unroll
    for (int i = 0; i < 4; ++i)
#pragma unroll
        for (int r = 0; r < 4; ++r) {
            long long row = m0 + wm + i * 16 + quad * 4 + r;
            float s = 0.f;
#pragma unroll
            for (int j = 0; j < 4; ++j) {
                float v = __expf(fast_tanh(acc[i][j][r]));
                s += v;
                Cg[row * (long long)N + (n0 + wn + j * 16 + l16)] = (bf16)v;
            }
#pragma unroll
            for (int msk = 1; msk < 16; msk <<= 1) s += __shfl_xor(s, msk);
            if (l16 == 0)
                atomicAdd(&rowsum[bz * batchR + row], s);
        }
}

// ---------------------------------------------------------------- 64(M)x128(N) tile, BK=64, NT
// MODE 0: C = A@B^T stored bf16 (proj). MODE 2: C = (A@B^T)/rowsum[row] stored fp32 (PV).
// 1024-block grids fix the under-subscription of the 128x128 version at N=512.
template <int MODE>
__global__ __launch_bounds__(256) void gemm64_nt(const bf16* __restrict__ A,
                                                 const bf16* __restrict__ Bm,
                                                 void* __restrict__ Cout,
                                                 const float* __restrict__ rowsum,
                                                 int M, int N, int K,
                                                 long long batchA, long long batchB,
                                                 long long batchC, long long batchR) {
    const long long bz = blockIdx.z;
    A  += bz * batchA;
    Bm += bz * batchB;

    __shared__ bf16 As[64 * 64];    // 8 KB
    __shared__ bf16 Bs[128 * 64];   // 16 KB
    __shared__ float rs[64];

    const int t    = threadIdx.x;
    const int lane = t & 63;
    const int wave = t >> 6;
    const int quad = lane >> 4;
    const int l16  = lane & 15;

    const int m0 = blockIdx.x * 64;
    const int n0 = blockIdx.y * 128;
    const int wn = wave * 32;

    floatx4 acc[4][2] = {};

    const int ra = t >> 3;
    const int ca = (((t & 7) ^ (ra & 7))) * 8;
    const long long rstep = 32LL * K;
    const bf16* Abase = A + (long long)(m0 + ra) * K + ca;
    const bf16* Bbase = Bm + (long long)(n0 + ra) * K + ca;

    const int cq0 = ((quad) ^ (l16 & 7)) * 8;
    const int cq1 = ((4 + quad) ^ (l16 & 7)) * 8;

    for (int k0 = 0; k0 < K; k0 += 64) {
#pragma unroll
        for (int i = 0; i < 2; ++i)
            gl_lds16(Abase + k0 + i * rstep, &As[(t + 256 * i) * 8]);
#pragma unroll
        for (int i = 0; i < 4; ++i)
            gl_lds16(Bbase + k0 + i * rstep, &Bs[(t + 256 * i) * 8]);
        __syncthreads();

#pragma unroll
        for (int s = 0; s < 2; ++s) {
            const int cq = s ? cq1 : cq0;
            bf16x8 af[4], bfr[2];
#pragma unroll
            for (int i = 0; i < 4; ++i)
                af[i] = *(const bf16x8*)(&As[(i * 16 + l16) * 64 + cq]);
#pragma unroll
            for (int j = 0; j < 2; ++j)
                bfr[j] = *(const bf16x8*)(&Bs[(wn + j * 16 + l16) * 64 + cq]);
#pragma unroll
            for (int i = 0; i < 4; ++i)
#pragma unroll
                for (int j = 0; j < 2; ++j)
                    acc[i][j] = __builtin_amdgcn_mfma_f32_16x16x32_bf16(af[i], bfr[j], acc[i][j], 0, 0, 0);
        }
        __syncthreads();
    }

    if (MODE == 2) {
        if (t < 64) rs[t] = rowsum[bz * batchR + m0 + t];
        __syncthreads();
        float* Og = (float*)Cout + bz * batchC;
#pragma unroll
        for (int i = 0; i < 4; ++i)
#pragma unroll
            for (int r = 0; r < 4; ++r) {
                int rl = i * 16 + quad * 4 + r;
                float inv = 1.0f / rs[rl];
                long long row = m0 + rl;
#pragma unroll
                for (int j = 0; j < 2; ++j)
                    Og[row * (long long)N + (n0 + wn + j * 16 + l16)] = acc[i][j][r] * inv;
            }
    } else {
        bf16* Cg = (bf16*)Cout + bz * batchC;
#pragma unroll
        for (int i = 0; i < 4; ++i)
#pragma unroll
            for (int r = 0; r < 4; ++r) {
                long long row = m0 + i * 16 + quad * 4 + r;
#pragma unroll
                for (int j = 0; j < 2; ++j)
                    Cg[row * (long long)N + (n0 + wn + j * 16 + l16)] = (bf16)acc[i][j][r];
            }
    }
}

// ----------------------------------------------------------------
extern "C" void kernel_launch(void* const* d_in, const int* in_sizes, int n_in,
                              void* d_out, int out_size, void* d_ws, size_t ws_size,
                              hipStream_t stream) {
    const int B = 8, S = 2048, D = 512;
    const float* x = (const float*)d_in[0];
    const float* W = (const float*)d_in[1];
    float* out = (float*)d_out;

    const size_t nx = (size_t)B * S * D;
    const size_t nw = (size_t)D * D;

    char* ws = (char*)d_ws;
    auto al = [](size_t v) { return (v + 255) & ~(size_t)255; };
    size_t off = 0;
    bf16* xb = (bf16*)(ws + off); off = al(off + nx * 2);          // x bf16 [B,S,D]
    bf16* xt = (bf16*)(ws + off); off = al(off + nx * 2);          // x^T bf16 [B,D,S]
    bf16* pb = (bf16*)(ws + off); off = al(off + nx * 2);          // proj bf16 [B,S,D]
    bf16* wt = (bf16*)(ws + off); off = al(off + nw * 2);          // W^T bf16 [D,D]
    float* rsum = (float*)(ws + off); off = al(off + (size_t)B * S * 4);
    bf16* sb = (bf16*)(ws + off);                                  // P_unnorm bf16
    const size_t full_need = off + (size_t)B * S * S * 2;
    const bool batched = (ws_size >= full_need);

    hipMemsetAsync(rsum, 0, (size_t)B * S * 4, stream);

    { dim3 g(S / 32, D / 32, B); cast_both<<<g, 256, 0, stream>>>(x, xb, xt, S, D); }
    { dim3 g(D / 32, D / 32, 1); cast_transpose<<<g, 256, 0, stream>>>(W, wt, D, D); }

    // proj: pb[BS,D] = xb @ wt^T   (64x128 tiles -> 1024 blocks)
    {
        dim3 g(B * S / 64, D / 128, 1);
        gemm64_nt<0><<<g, 256, 0, stream>>>(xb, wt, (void*)pb, nullptr, B * S, D, D, 0, 0, 0, 0);
    }

    const long long sd = (long long)S * D;
    const long long ss = (long long)S * S;

    if (batched) {
        // P_un = exp(tanh(pb @ xb^T)) + rowsums
        dim3 g2(S / 128, S / 128, B);
        gemm128_score<<<g2, 256, 0, stream>>>(pb, xb, sb, rsum, S, S, D, sd, sd, ss, S);
        // out = (P_un @ xt^T) / rowsum   (64x128 tiles -> 1024 blocks)
        dim3 g4(S / 64, D / 128, B);
        gemm64_nt<2><<<g4, 256, 0, stream>>>(sb, xt, (void*)out, rsum, S, D, S, ss, sd, sd, S);
    } else {
        for (int b = 0; b < B; ++b) {
            dim3 g2(S / 128, S / 128, 1);
            gemm128_score<<<g2, 256, 0, stream>>>(pb + (size_t)b * sd, xb + (size_t)b * sd,
                                                  sb, rsum + (size_t)b * S, S, S, D, 0, 0, 0, 0);
            dim3 g4(S / 64, D / 128, 1);
            gemm64_nt<2><<<g4, 256, 0, stream>>>(sb, xt + (size_t)b * sd,
                                                 (void*)(out + (size_t)b * sd), rsum + (size_t)b * S,
                                                 S, D, S, 0, 0, 0, 0);
        }
    }
}